// Round 3
// baseline (248.241 us; speedup 1.0000x reference)
//
#include <hip/hip_runtime.h>

typedef float f32x4 __attribute__((ext_vector_type(4)));
typedef short bf16x8 __attribute__((ext_vector_type(8)));   // 8 bf16 in 4 VGPRs (MFMA A/B operand)
typedef unsigned short u16x4 __attribute__((ext_vector_type(4)));

#define NS 8192
#define NB 16
#define NE 128
#define GS 4   // s-values per block (one per wave)

// Pack two f32 -> two bf16 (round-half-up via +0x8000, then v_perm grabs high halves).
__device__ __forceinline__ unsigned pack_bf16_rn(float lo, float hi) {
  union { float f; unsigned u; } a, b; a.f = lo; b.f = hi;
  return __builtin_amdgcn_perm(b.u + 0x8000u, a.u + 0x8000u, 0x07060302u);
}
// 8 consecutive f32 -> one MFMA bf16x8 fragment
__device__ __forceinline__ bf16x8 frag_from_f32(const float* p) {
  f32x4 lo = *(const f32x4*)p;
  f32x4 hi = *(const f32x4*)(p + 4);
  union { bf16x8 v; unsigned u[4]; } r;
  r.u[0] = pack_bf16_rn(lo[0], lo[1]);
  r.u[1] = pack_bf16_rn(lo[2], lo[3]);
  r.u[2] = pack_bf16_rn(hi[0], hi[1]);
  r.u[3] = pack_bf16_rn(hi[2], hi[3]);
  return r.v;
}
__device__ __forceinline__ u16x4 pack4(f32x4 v) {
  union { u16x4 s; unsigned u[2]; } r;
  r.u[0] = pack_bf16_rn(v[0], v[1]);
  r.u[1] = pack_bf16_rn(v[2], v[3]);
  return r.s;
}

__global__ __launch_bounds__(256, 4)
void nsa_fused(const float* __restrict__ x,
               const float* __restrict__ Wk,
               const float* __restrict__ bk,
               const float* __restrict__ Wv,
               const float* __restrict__ bv,
               float* __restrict__ out)
{
  // Kt/Vt: [mat(2)][s(GS)][e(128)][16 shorts] bf16 with per-row 16B-granule XOR swizzle:
  //   physical short offset within row = ((o>>3) ^ ((e>>2)&1))*8 + (o&7)
  // -> KV 8B writes and attention b128 reads are both 2-way (free, m136).
  // The V slice of wave w's own s is DEAD after vf load; reused as that wave's P buffer
  // (rotate swizzle col'=(col+8*ln)&127) -> no separate pbuf -> 32.8 KB LDS -> 4 blocks/CU.
  __shared__ __align__(16) unsigned short kt[2 * GS * NE * 16];
  __shared__ __align__(16) unsigned short zbuf[32];   // 64B zeros: K-dim padding (b=16..31)

  const int tid  = threadIdx.x;
  const int wave = tid >> 6;
  const int lane = tid & 63;
  const int q    = lane >> 4;    // quad 0..3
  const int ln   = lane & 15;
  const int s0   = blockIdx.x * GS;

  if (tid < 32) zbuf[tid] = 0;

  bf16x8 xof[4];   // A-frags for the out-GEMM (this wave's own s), captured in KV phase

  // ---------------- KV phase: K = X@Wk^T + bk, V = X@Wv^T + bv ----------------
  // wave w owns e-tiles {2w, 2w+1}; weight B-frags held in registers for all 4 s.
  {
    const float* const Wm[2] = { Wk, Wv };
    bf16x8 wf[2][2][4];   // [mat][ntl][ks]
    float  bias[2][2];
    #pragma unroll
    for (int mat = 0; mat < 2; ++mat)
      #pragma unroll
      for (int ntl = 0; ntl < 2; ++ntl) {
        const int e = (wave * 2 + ntl) * 16 + ln;
        #pragma unroll
        for (int ks = 0; ks < 4; ++ks)
          wf[mat][ntl][ks] = frag_from_f32(Wm[mat] + e * NE + ks * 32 + q * 8);
      }
    #pragma unroll
    for (int ntl = 0; ntl < 2; ++ntl) {
      const int e = (wave * 2 + ntl) * 16 + ln;
      bias[0][ntl] = bk[e];
      bias[1][ntl] = bv[e];
    }

    for (int mt = 0; mt < GS; ++mt) {            // m-tile = one s (16 b-rows)
      const int s = s0 + mt;
      bf16x8 xf[4];
      #pragma unroll
      for (int ks = 0; ks < 4; ++ks)
        xf[ks] = frag_from_f32(x + (s * NB + ln) * NE + ks * 32 + q * 8);
      if (mt == wave) {
        #pragma unroll
        for (int ks = 0; ks < 4; ++ks) xof[ks] = xf[ks];
      }
      #pragma unroll
      for (int mat = 0; mat < 2; ++mat)
        #pragma unroll
        for (int ntl = 0; ntl < 2; ++ntl) {
          f32x4 acc = { bias[mat][ntl], bias[mat][ntl], bias[mat][ntl], bias[mat][ntl] };
          #pragma unroll
          for (int ks = 0; ks < 4; ++ks)
            acc = __builtin_amdgcn_mfma_f32_16x16x32_bf16(xf[ks], wf[mat][ntl][ks], acc, 0, 0, 0);
          // C/D: col=e (lane&15), rows b=q*4+r -> swizzled 8B write to Kt/Vt[e][...]
          const int e = (wave * 2 + ntl) * 16 + ln;
          const int g = (e >> 2) & 1;
          const int o = (((q >> 1) ^ g) << 3) + ((q & 1) << 2);
          *(u16x4*)&kt[((mat * GS + mt) * NE + e) * 16 + o] = pack4(acc);
        }
    }
  }
  __syncthreads();

  // ---------------- attention phase: wave handles s = s0 + wave ----------------
  {
    const int sw  = s0 + wave;
    const int smt = wave;

    // A-frags for scores^T = V^T K: A[m=f][k=b] = Vt[f][b]; pad b>=16 with zeros
    bf16x8 vf[8];
    #pragma unroll
    for (int mt = 0; mt < 8; ++mt) {
      const int f = mt * 16 + ln;
      const int g = (f >> 2) & 1;
      const unsigned short* src =
          (q < 2) ? &kt[((GS + smt) * NE + f) * 16 + (((q ^ g) & 1) << 3)] : zbuf;
      vf[mt] = *(const bf16x8*)src;
    }

    // V slice of own s is now dead -> P buffer (16 rows x 128 shorts, rotate swizzle)
    unsigned short* pw = &kt[(GS + smt) * NE * 16];

    const float scale = 1.4426950408889634f / 90.50966799187809f;  // log2(e)/sqrt(8192)

    for (int eb = 0; eb < 8; ++eb) {
      const int e  = eb * 16 + ln;
      const int ge = (e >> 2) & 1;
      // B-frag: B[k=b][n=e] = Kt[e][b]
      const unsigned short* ksrc =
          (q < 2) ? &kt[(smt * NE + e) * 16 + (((q ^ ge) & 1) << 3)] : zbuf;
      const bf16x8 kf = *(const bf16x8*)ksrc;

      f32x4 sc[8];   // lane(ln,q) reg r = scores[e=16eb+ln][f=16mt+4q+r]
      #pragma unroll
      for (int mt = 0; mt < 8; ++mt) {
        const f32x4 z = { 0.f, 0.f, 0.f, 0.f };
        sc[mt] = __builtin_amdgcn_mfma_f32_16x16x32_bf16(vf[mt], kf, z, 0, 0, 0);
      }

      // softmax over f for fixed e: 32 in-lane values + reduce across quads (xor 16,32)
      float mx = -3.4e38f;
      #pragma unroll
      for (int mt = 0; mt < 8; ++mt)
        #pragma unroll
        for (int r = 0; r < 4; ++r) mx = fmaxf(mx, sc[mt][r]);
      mx = fmaxf(mx, __shfl_xor(mx, 16));
      mx = fmaxf(mx, __shfl_xor(mx, 32));
      const float nmx = -mx * scale;
      float sum = 0.f;
      #pragma unroll
      for (int mt = 0; mt < 8; ++mt)
        #pragma unroll
        for (int r = 0; r < 4; ++r) {
          const float p = __builtin_amdgcn_exp2f(__builtin_fmaf(sc[mt][r], scale, nmx));
          sc[mt][r] = p;
          sum += p;
        }
      sum += __shfl_xor(sum, 16);
      sum += __shfl_xor(sum, 32);
      const float inv_l = __builtin_amdgcn_rcpf(sum);

      // P rows for this e-block -> pw row ln, rotate swizzle col'=(col+8*ln)&127
      #pragma unroll
      for (int mt = 0; mt < 8; ++mt) {
        const int col = (mt * 16 + q * 4 + 8 * ln) & 127;
        *(u16x4*)&pw[ln * 128 + col] = pack4(sc[mt]);
      }

      // out n-tile eb: D[m=b][n=e] = sum_f X[b][f] * P[e][f]
      f32x4 oacc = { 0.f, 0.f, 0.f, 0.f };
      #pragma unroll
      for (int ks = 0; ks < 4; ++ks) {
        const int col = (ks * 32 + q * 8 + 8 * ln) & 127;
        const bf16x8 pf = *(const bf16x8*)&pw[ln * 128 + col];
        oacc = __builtin_amdgcn_mfma_f32_16x16x32_bf16(xof[ks], pf, oacc, 0, 0, 0);
      }
      #pragma unroll
      for (int r = 0; r < 4; ++r)
        out[(sw * NB + q * 4 + r) * NE + e] = oacc[r] * inv_l;
    }
  }
}

extern "C" void kernel_launch(void* const* d_in, const int* in_sizes, int n_in,
                              void* d_out, int out_size, void* d_ws, size_t ws_size,
                              hipStream_t stream)
{
  const float* x  = (const float*)d_in[0];
  const float* Wk = (const float*)d_in[1];
  const float* bk = (const float*)d_in[2];
  const float* Wv = (const float*)d_in[3];
  const float* bv = (const float*)d_in[4];
  float* o = (float*)d_out;

  dim3 grid(NS / GS), block(256);
  hipLaunchKernelGGL(nsa_fused, grid, block, 0, stream, x, Wk, bk, Wv, bv, o);
}

// Round 4
// 163.174 us; speedup vs baseline: 1.5213x; 1.5213x over previous
//
#include <hip/hip_runtime.h>

typedef float f32x4 __attribute__((ext_vector_type(4)));
typedef short bf16x8 __attribute__((ext_vector_type(8)));   // 8 bf16 in 4 VGPRs (MFMA A/B operand)
typedef unsigned short u16x4 __attribute__((ext_vector_type(4)));

#define NS 8192
#define NB 16
#define NE 128
#define GS 4   // s-values per block (one per wave)
// log2(e)/sqrt(8192), folded into Wk/bk by the prelude
#define SCALE_K (1.4426950408889634f / 90.50966799187809f)

// Pack two f32 -> two bf16 (round-half-up via +0x8000, then v_perm grabs high halves).
__device__ __forceinline__ unsigned pack_bf16_rn(float lo, float hi) {
  union { float f; unsigned u; } a, b; a.f = lo; b.f = hi;
  return __builtin_amdgcn_perm(b.u + 0x8000u, a.u + 0x8000u, 0x07060302u);
}
__device__ __forceinline__ bf16x8 frag_from_f32(const float* p) {
  f32x4 lo = *(const f32x4*)p;
  f32x4 hi = *(const f32x4*)(p + 4);
  union { bf16x8 v; unsigned u[4]; } r;
  r.u[0] = pack_bf16_rn(lo[0], lo[1]);
  r.u[1] = pack_bf16_rn(lo[2], lo[3]);
  r.u[2] = pack_bf16_rn(hi[0], hi[1]);
  r.u[3] = pack_bf16_rn(hi[2], hi[3]);
  return r.v;
}
__device__ __forceinline__ u16x4 pack4(f32x4 v) {
  union { u16x4 s; unsigned u[2]; } r;
  r.u[0] = pack_bf16_rn(v[0], v[1]);
  r.u[1] = pack_bf16_rn(v[2], v[3]);
  return r.s;
}

// ---------- prelude: W -> bf16 fragments in d_ws (once per launch, 4096 threads) ----------
// wsW layout: [mat(2)][ntile(8)][ks(4)][lane(64)][8 shorts]  -> frag load = 1 coalesced b128
// Wk, bk pre-scaled by SCALE_K so softmax is exp2(score) with no per-element multiply.
__global__ __launch_bounds__(256)
void nsa_prep(const float* __restrict__ Wk, const float* __restrict__ bk,
              const float* __restrict__ Wv, const float* __restrict__ bv,
              unsigned short* __restrict__ wsW, float* __restrict__ wsB)
{
  const int t    = blockIdx.x * 256 + threadIdx.x;   // 0..4095
  const int lane = t & 63, ks = (t >> 6) & 3, nt = (t >> 8) & 7, mat = (t >> 11) & 1;
  const int q = lane >> 4, ln = lane & 15;
  const float sc = mat ? 1.0f : SCALE_K;
  const float* W = (mat ? Wv : Wk) + (nt * 16 + ln) * NE + ks * 32 + q * 8;
  union { bf16x8 v; unsigned u[4]; } r;
  #pragma unroll
  for (int i = 0; i < 4; ++i)
    r.u[i] = pack_bf16_rn(W[2 * i] * sc, W[2 * i + 1] * sc);
  *(bf16x8*)(wsW + t * 8) = r.v;
  if (t < NE)          wsB[t] = bk[t] * SCALE_K;
  else if (t < 2 * NE) wsB[t] = bv[t - NE];
}

// ---------- main fused kernel ----------
__global__ __launch_bounds__(256, 4)
void nsa_fused(const float* __restrict__ x,
               const unsigned short* __restrict__ wsW,
               const float* __restrict__ wsB,
               float* __restrict__ out)
{
  // Kt/Vt: [mat(2)][s(GS)][e(128)][16 shorts] bf16, 16B-granule XOR swizzle per row.
  // V slice of wave w's own s is dead after vf load -> reused as its P buffer.
  __shared__ __align__(16) unsigned short kt[2 * GS * NE * 16];
  __shared__ __align__(16) unsigned short zbuf[32];   // 64B zeros: K-dim pad (b=16..31)

  const int tid  = threadIdx.x;
  const int wave = tid >> 6;
  const int lane = tid & 63;
  const int q    = lane >> 4;
  const int ln   = lane & 15;
  const int s0   = blockIdx.x * GS;

  if (tid < 32) zbuf[tid] = 0;

  bf16x8 xf[4];   // after KV phase holds this wave's own-s A-frags (mt order ends at own s)

  // ---------------- KV phase ----------------
  {
    bf16x8 wf[2][2][4];   // all 16 weight frags: single b128 loads, no conversion VALU
    float  bias[2][2];
    #pragma unroll
    for (int mat = 0; mat < 2; ++mat)
      #pragma unroll
      for (int ntl = 0; ntl < 2; ++ntl) {
        const int nt = wave * 2 + ntl;
        #pragma unroll
        for (int ks = 0; ks < 4; ++ks)
          wf[mat][ntl][ks] = *(const bf16x8*)(wsW + (((mat * 8 + nt) * 4 + ks) * 64 + lane) * 8);
        bias[mat][ntl] = wsB[mat * NE + nt * 16 + ln];
      }

    #pragma unroll
    for (int i = 0; i < GS; ++i) {
      const int mt = (wave + 1 + i) & (GS - 1);     // end at mt==wave so xf == own-s frags
      const int s  = s0 + mt;
      #pragma unroll
      for (int ks = 0; ks < 4; ++ks)
        xf[ks] = frag_from_f32(x + (s * NB + ln) * NE + ks * 32 + q * 8);
      #pragma unroll
      for (int mat = 0; mat < 2; ++mat)
        #pragma unroll
        for (int ntl = 0; ntl < 2; ++ntl) {
          f32x4 acc = { bias[mat][ntl], bias[mat][ntl], bias[mat][ntl], bias[mat][ntl] };
          #pragma unroll
          for (int ks = 0; ks < 4; ++ks)
            acc = __builtin_amdgcn_mfma_f32_16x16x32_bf16(xf[ks], wf[mat][ntl][ks], acc, 0, 0, 0);
          const int e = (wave * 2 + ntl) * 16 + ln;
          const int g = (e >> 2) & 1;
          const int o = (((q >> 1) ^ g) << 3) + ((q & 1) << 2);
          *(u16x4*)&kt[((mat * GS + mt) * NE + e) * 16 + o] = pack4(acc);
        }
    }
  }
  __syncthreads();

  // ---------------- attention phase: wave handles s = s0 + wave ----------------
  {
    const int sw  = s0 + wave;
    const int smt = wave;

    // A-frags for scores^T = V^T K': A[m=f][k=b]; b>=16 zero-padded via zbuf broadcast
    bf16x8 vf[8];
    #pragma unroll
    for (int mt = 0; mt < 8; ++mt) {
      const int f = mt * 16 + ln;
      const int g = (f >> 2) & 1;
      const unsigned short* src =
          (q < 2) ? &kt[((GS + smt) * NE + f) * 16 + (((q ^ g) & 1) << 3)] : zbuf;
      vf[mt] = *(const bf16x8*)src;
    }

    // own V slice now dead -> P buffer (16 x 128 shorts, rotate swizzle)
    unsigned short* pw = &kt[(GS + smt) * NE * 16];

    #pragma unroll 1
    for (int eb = 0; eb < 8; ++eb) {
      const int e  = eb * 16 + ln;
      const int ge = (e >> 2) & 1;
      const unsigned short* ksrc =
          (q < 2) ? &kt[(smt * NE + e) * 16 + (((q ^ ge) & 1) << 3)] : zbuf;
      const bf16x8 kf = *(const bf16x8*)ksrc;

      // streaming: one score tile live at a time; no max-sub (|score*scale| << 1),
      // scale pre-folded into K' -> p = exp2(score') directly
      f32x4 sum4 = { 0.f, 0.f, 0.f, 0.f };
      #pragma unroll
      for (int mt = 0; mt < 8; ++mt) {
        const f32x4 z = { 0.f, 0.f, 0.f, 0.f };
        f32x4 sc = __builtin_amdgcn_mfma_f32_16x16x32_bf16(vf[mt], kf, z, 0, 0, 0);
        f32x4 p;
        #pragma unroll
        for (int r = 0; r < 4; ++r) p[r] = __builtin_amdgcn_exp2f(sc[r]);
        sum4 += p;
        const int col = (mt * 16 + q * 4 + 8 * ln) & 127;
        *(u16x4*)&pw[ln * 128 + col] = pack4(p);
      }
      float sum = (sum4[0] + sum4[1]) + (sum4[2] + sum4[3]);
      sum += __shfl_xor(sum, 16);
      sum += __shfl_xor(sum, 32);
      const float inv_l = __builtin_amdgcn_rcpf(sum);   // per-e; lane-matched to out col

      // out n-tile eb: D[m=b][n=e] = sum_f X[b][f] * P[e][f]  (P unnormalized; /l in epilogue)
      f32x4 oacc = { 0.f, 0.f, 0.f, 0.f };
      #pragma unroll
      for (int ks = 0; ks < 4; ++ks) {
        const int col = (ks * 32 + q * 8 + 8 * ln) & 127;
        const bf16x8 pf = *(const bf16x8*)&pw[ln * 128 + col];
        oacc = __builtin_amdgcn_mfma_f32_16x16x32_bf16(xf[ks], pf, oacc, 0, 0, 0);
      }
      #pragma unroll
      for (int r = 0; r < 4; ++r)
        out[(sw * NB + q * 4 + r) * NE + e] = oacc[r] * inv_l;
    }
  }
}

extern "C" void kernel_launch(void* const* d_in, const int* in_sizes, int n_in,
                              void* d_out, int out_size, void* d_ws, size_t ws_size,
                              hipStream_t stream)
{
  const float* x  = (const float*)d_in[0];
  const float* Wk = (const float*)d_in[1];
  const float* bk = (const float*)d_in[2];
  const float* Wv = (const float*)d_in[3];
  const float* bv = (const float*)d_in[4];
  float* o = (float*)d_out;

  unsigned short* wsW = (unsigned short*)d_ws;                  // 64 KiB
  float*          wsB = (float*)((char*)d_ws + 64 * 1024);      // 1 KiB

  hipLaunchKernelGGL(nsa_prep, dim3(16), dim3(256), 0, stream, Wk, bk, Wv, bv, wsW, wsB);
  hipLaunchKernelGGL(nsa_fused, dim3(NS / GS), dim3(256), 0, stream, x, wsW, wsB, o);
}

// Round 5
// 153.713 us; speedup vs baseline: 1.6150x; 1.0616x over previous
//
#include <hip/hip_runtime.h>

typedef float f32x4 __attribute__((ext_vector_type(4)));
typedef short bf16x8 __attribute__((ext_vector_type(8)));   // 8 bf16 in 4 VGPRs (MFMA A/B operand)
typedef unsigned short u16x4 __attribute__((ext_vector_type(4)));

#define NS 8192
#define NB 16
#define NE 128
#define GS 4   // s-values per block (one per wave)
// log2(e)/sqrt(8192), folded into Wk/bk by the prelude
#define SCALE_K (1.4426950408889634f / 90.50966799187809f)

// Pack two f32 -> two bf16 RNE-ish (round-half-up via +0x8000; perm takes high halves).
__device__ __forceinline__ unsigned pack_bf16_rn(float lo, float hi) {
  union { float f; unsigned u; } a, b; a.f = lo; b.f = hi;
  return __builtin_amdgcn_perm(b.u + 0x8000u, a.u + 0x8000u, 0x07060302u);
}
// Truncating pack (bias cancels in p/l since l is summed from these same bf16 values)
__device__ __forceinline__ unsigned pack_bf16_tr(float lo, float hi) {
  union { float f; unsigned u; } a, b; a.f = lo; b.f = hi;
  return __builtin_amdgcn_perm(b.u, a.u, 0x07060302u);
}
__device__ __forceinline__ bf16x8 frag_from_f32(const float* p) {
  f32x4 lo = *(const f32x4*)p;
  f32x4 hi = *(const f32x4*)(p + 4);
  union { bf16x8 v; unsigned u[4]; } r;
  r.u[0] = pack_bf16_rn(lo[0], lo[1]);
  r.u[1] = pack_bf16_rn(lo[2], lo[3]);
  r.u[2] = pack_bf16_rn(hi[0], hi[1]);
  r.u[3] = pack_bf16_rn(hi[2], hi[3]);
  return r.v;
}
__device__ __forceinline__ u16x4 pack4_rn(f32x4 v) {
  union { u16x4 s; unsigned u[2]; } r;
  r.u[0] = pack_bf16_rn(v[0], v[1]);
  r.u[1] = pack_bf16_rn(v[2], v[3]);
  return r.s;
}
__device__ __forceinline__ u16x4 pack4_tr(f32x4 v) {
  union { u16x4 s; unsigned u[2]; } r;
  r.u[0] = pack_bf16_tr(v[0], v[1]);
  r.u[1] = pack_bf16_tr(v[2], v[3]);
  return r.s;
}

// ---------- prelude: W -> bf16 fragments in d_ws (once per launch) ----------
// wsW layout: [mat(2)][ntile(8)][ks(4)][lane(64)][8 shorts]  -> frag load = 1 coalesced b128
// Wk, bk pre-scaled by SCALE_K so softmax is exp2(score) with no per-element multiply.
__global__ __launch_bounds__(256)
void nsa_prep(const float* __restrict__ Wk, const float* __restrict__ bk,
              const float* __restrict__ Wv, const float* __restrict__ bv,
              unsigned short* __restrict__ wsW, float* __restrict__ wsB)
{
  const int t    = blockIdx.x * 256 + threadIdx.x;   // 0..4095
  const int lane = t & 63, ks = (t >> 6) & 3, nt = (t >> 8) & 7, mat = (t >> 11) & 1;
  const int q = lane >> 4, ln = lane & 15;
  const float sc = mat ? 1.0f : SCALE_K;
  const float* W = (mat ? Wv : Wk) + (nt * 16 + ln) * NE + ks * 32 + q * 8;
  union { bf16x8 v; unsigned u[4]; } r;
  #pragma unroll
  for (int i = 0; i < 4; ++i)
    r.u[i] = pack_bf16_rn(W[2 * i] * sc, W[2 * i + 1] * sc);
  *(bf16x8*)(wsW + t * 8) = r.v;
  if (t < NE)          wsB[t] = bk[t] * SCALE_K;
  else if (t < 2 * NE) wsB[t] = bv[t - NE];
}

// ---------- main fused kernel ----------
__global__ __launch_bounds__(256, 4)
void nsa_fused(const float* __restrict__ x,
               const unsigned short* __restrict__ wsW,
               const float* __restrict__ wsB,
               float* __restrict__ out)
{
  // Kt/Vt: [mat(2)][s(GS)][e(128)][16 shorts] bf16, 16B-granule XOR swizzle per row
  // (group bit g = (ln>>2)&1 -- identical for every access site, hoisted below).
  // V slice of wave w's own s is dead after vf load -> reused as its P buffer.
  __shared__ __align__(16) unsigned short kt[2 * GS * NE * 16];
  __shared__ __align__(16) unsigned short zbuf[32];   // 64B zeros: K-dim pad (b=16..31)

  const int tid  = threadIdx.x;
  const int wave = tid >> 6;
  const int lane = tid & 63;
  const int q    = lane >> 4;
  const int ln   = lane & 15;
  const int g    = (ln >> 2) & 1;      // swizzle group bit (same at every site)
  const int s0   = blockIdx.x * GS;

  if (tid < 32) zbuf[tid] = 0;

  bf16x8 xf[4];   // after KV phase holds this wave's own-s A-frags (mt order ends at own s)

  // ---------------- KV phase ----------------
  {
    bf16x8 wf[2][2][4];   // all 16 weight frags: single b128 loads, no conversion VALU
    float  bias[2][2];
    #pragma unroll
    for (int mat = 0; mat < 2; ++mat)
      #pragma unroll
      for (int ntl = 0; ntl < 2; ++ntl) {
        const int nt = wave * 2 + ntl;
        #pragma unroll
        for (int ks = 0; ks < 4; ++ks)
          wf[mat][ntl][ks] = *(const bf16x8*)(wsW + (((mat * 8 + nt) * 4 + ks) * 64 + lane) * 8);
        bias[mat][ntl] = wsB[mat * NE + nt * 16 + ln];
      }

    const int o = (((q >> 1) ^ g) << 3) + ((q & 1) << 2);   // swizzled 8B-write offset
    #pragma unroll
    for (int i = 0; i < GS; ++i) {
      const int mt = (wave + 1 + i) & (GS - 1);     // end at mt==wave so xf == own-s frags
      const int s  = s0 + mt;
      #pragma unroll
      for (int ks = 0; ks < 4; ++ks)
        xf[ks] = frag_from_f32(x + (s * NB + ln) * NE + ks * 32 + q * 8);
      #pragma unroll
      for (int mat = 0; mat < 2; ++mat)
        #pragma unroll
        for (int ntl = 0; ntl < 2; ++ntl) {
          f32x4 acc = { bias[mat][ntl], bias[mat][ntl], bias[mat][ntl], bias[mat][ntl] };
          #pragma unroll
          for (int ks = 0; ks < 4; ++ks)
            acc = __builtin_amdgcn_mfma_f32_16x16x32_bf16(xf[ks], wf[mat][ntl][ks], acc, 0, 0, 0);
          const int e = (wave * 2 + ntl) * 16 + ln;
          *(u16x4*)&kt[((mat * GS + mt) * NE + e) * 16 + o] = pack4_rn(acc);
        }
    }
  }
  __syncthreads();

  // ---------------- attention phase: wave handles s = s0 + wave ----------------
  {
    const int sw  = s0 + wave;
    const int smt = wave;
    const int ro  = ((q ^ g) & 1) << 3;   // swizzled 16B-read offset within row

    // A-frags for scores^T = V^T K': A[m=f][k=b]; b>=16 zero-padded via zbuf broadcast
    bf16x8 vf[8];
    #pragma unroll
    for (int mt = 0; mt < 8; ++mt) {
      const unsigned short* src =
          (q < 2) ? &kt[((GS + smt) * NE + mt * 16 + ln) * 16 + ro] : zbuf;
      vf[mt] = *(const bf16x8*)src;
    }

    // own V slice now dead -> P buffer (16 x 128 shorts, rotate swizzle)
    unsigned short* pw = &kt[(GS + smt) * NE * 16];

    // all-ones A-frag: D[m][e] = sum_f P[e][f] -> softmax denominator on the MFMA pipe
    union { bf16x8 v; unsigned u[4]; } onesu;
    #pragma unroll
    for (int i = 0; i < 4; ++i) onesu.u[i] = 0x3F803F80u;   // bf16 1.0 pairs
    const bf16x8 ones = onesu.v;

    // kf base (row advances by eb*16 rows = 256 shorts -> immediate offsets)
    const unsigned short* kbase = (q < 2) ? &kt[(smt * NE + ln) * 16 + ro] : zbuf;
    const int kstep = (q < 2) ? 256 : 0;

    bf16x8 kf = *(const bf16x8*)kbase;

    #pragma unroll 2
    for (int eb = 0; eb < 8; ++eb) {
      const bf16x8 kcur = kf;
      if (eb < 7) kf = *(const bf16x8*)(kbase + (eb + 1) * kstep);   // prefetch next

      // streaming scores -> exp2 -> truncated bf16 P -> LDS (no max-sub; scale pre-folded)
      #pragma unroll
      for (int mt = 0; mt < 8; ++mt) {
        const f32x4 z = { 0.f, 0.f, 0.f, 0.f };
        f32x4 sc = __builtin_amdgcn_mfma_f32_16x16x32_bf16(vf[mt], kcur, z, 0, 0, 0);
        f32x4 p;
        #pragma unroll
        for (int r = 0; r < 4; ++r) p[r] = __builtin_amdgcn_exp2f(sc[r]);
        const int col = (mt * 16 + q * 4 + 8 * ln) & 127;
        *(u16x4*)&pw[ln * 128 + col] = pack4_tr(p);
      }

      // out n-tile: D[m=b][n=e] = sum_f X[b][f] * P[e][f]; denominator via ones-MFMA
      f32x4 oacc = { 0.f, 0.f, 0.f, 0.f };
      f32x4 lacc = { 0.f, 0.f, 0.f, 0.f };
      #pragma unroll
      for (int ks = 0; ks < 4; ++ks) {
        const int col = (ks * 32 + q * 8 + 8 * ln) & 127;
        const bf16x8 pf = *(const bf16x8*)&pw[ln * 128 + col];
        oacc = __builtin_amdgcn_mfma_f32_16x16x32_bf16(xf[ks], pf, oacc, 0, 0, 0);
        lacc = __builtin_amdgcn_mfma_f32_16x16x32_bf16(ones,   pf, lacc, 0, 0, 0);
      }
      const float inv_l = __builtin_amdgcn_rcpf(lacc[0]);   // D col = ln -> lane-matched
      const int e = eb * 16 + ln;
      #pragma unroll
      for (int r = 0; r < 4; ++r)
        out[(sw * NB + q * 4 + r) * NE + e] = oacc[r] * inv_l;
    }
  }
}

extern "C" void kernel_launch(void* const* d_in, const int* in_sizes, int n_in,
                              void* d_out, int out_size, void* d_ws, size_t ws_size,
                              hipStream_t stream)
{
  const float* x  = (const float*)d_in[0];
  const float* Wk = (const float*)d_in[1];
  const float* bk = (const float*)d_in[2];
  const float* Wv = (const float*)d_in[3];
  const float* bv = (const float*)d_in[4];
  float* o = (float*)d_out;

  unsigned short* wsW = (unsigned short*)d_ws;                  // 64 KiB
  float*          wsB = (float*)((char*)d_ws + 64 * 1024);      // 1 KiB

  hipLaunchKernelGGL(nsa_prep, dim3(16), dim3(256), 0, stream, Wk, bk, Wv, bv, wsW, wsB);
  hipLaunchKernelGGL(nsa_fused, dim3(NS / GS), dim3(256), 0, stream, x, wsW, wsB, o);
}